// Round 2
// baseline (228.485 us; speedup 1.0000x reference)
//
#include <hip/hip_runtime.h>
#include <math.h>

#define N_TOK 16384
#define D_MODEL 2048
#define N_EXP 64
#define CAPACITY 640
#define NREP 8

#define BK 64
#define NSTAGE (D_MODEL / BK)  // 32
#define LPW 72                 // W LDS row pitch in halves (144B: bank-uniform, 16B-aligned)

typedef __attribute__((ext_vector_type(8))) _Float16 h8;
typedef __attribute__((ext_vector_type(4))) float f4;

// ---------------- K12: fused MFMA fp16-split GEMM + softmax/top2/hist/z -----
// 256 blocks x 256 thr; block = 64 tokens x 64 experts x K=2048.
// x: global -> registers in A-fragment layout (no LDS). W: LDS, double-buffered,
// 1 barrier/stage. 3-term split: logits=(xh·wh' + (xl·wh' + xh·wl')·2^-10)·2^-10.
__global__ __launch_bounds__(256, 1) void k12_gemm_softmax(
    const float* __restrict__ x, const float* __restrict__ W,
    float* __restrict__ rw_out, int2* __restrict__ top12,
    float2* __restrict__ wts, int* __restrict__ histR,
    float* __restrict__ zR) {
  __shared__ __align__(16) _Float16 WHs[2][64][LPW];
  __shared__ __align__(16) _Float16 WLs[2][64][LPW];
  __shared__ float slog[64][65];
  __shared__ float zred[4];

  const int t = threadIdx.x;
  const int lane = t & 63;
  const int wid = t >> 6;
  const int m0 = blockIdx.x * 64;
  const int rep = blockIdx.x & (NREP - 1);

  const int we = t >> 2;        // W staging: expert row
  const int wc = (t & 3) * 16;  // W staging: col base (floats == halves idx)
  const int frow = lane & 15;   // A/B fragment row
  const int fk = (lane >> 4) * 8;

  const float* wg = W + (size_t)we * D_MODEL + wc;
  const float* xg = x + (size_t)(m0 + wid * 16 + frow) * D_MODEL + fk;

  float4 wreg[2][4], xreg[2][4];
  h8 afh[2][2], afl[2][2];
  f4 acc1[4], acc2[4];
#pragma unroll
  for (int i = 0; i < 4; i++) {
    acc1[i] = (f4)(0.f);
    acc2[i] = (f4)(0.f);
  }

#define LOAD_W(slot, s)                        \
  {                                            \
    const float* p_ = wg + (s) * BK;           \
    wreg[slot][0] = *(const float4*)(p_);      \
    wreg[slot][1] = *(const float4*)(p_ + 4);  \
    wreg[slot][2] = *(const float4*)(p_ + 8);  \
    wreg[slot][3] = *(const float4*)(p_ + 12); \
  }
#define LOAD_X(slot, s)                        \
  {                                            \
    const float* p_ = xg + (s) * BK;           \
    xreg[slot][0] = *(const float4*)(p_);      \
    xreg[slot][1] = *(const float4*)(p_ + 4);  \
    xreg[slot][2] = *(const float4*)(p_ + 32); \
    xreg[slot][3] = *(const float4*)(p_ + 36); \
  }

#define CVTSTORE_W(slot, buf)                                           \
  {                                                                     \
    float wf[16] = {wreg[slot][0].x, wreg[slot][0].y, wreg[slot][0].z,  \
                    wreg[slot][0].w, wreg[slot][1].x, wreg[slot][1].y,  \
                    wreg[slot][1].z, wreg[slot][1].w, wreg[slot][2].x,  \
                    wreg[slot][2].y, wreg[slot][2].z, wreg[slot][2].w,  \
                    wreg[slot][3].x, wreg[slot][3].y, wreg[slot][3].z,  \
                    wreg[slot][3].w};                                   \
    h8 h0, h1, l0, l1;                                                  \
    _Pragma("unroll") for (int j = 0; j < 8; j++) {                     \
      float s0 = wf[j] * 1024.f;                                        \
      _Float16 a_ = (_Float16)s0;                                       \
      h0[j] = a_;                                                       \
      l0[j] = (_Float16)((s0 - (float)a_) * 1024.f);                    \
      float s1 = wf[j + 8] * 1024.f;                                    \
      _Float16 b_ = (_Float16)s1;                                       \
      h1[j] = b_;                                                       \
      l1[j] = (_Float16)((s1 - (float)b_) * 1024.f);                    \
    }                                                                   \
    *(h8*)&WHs[buf][we][wc] = h0;                                       \
    *(h8*)&WHs[buf][we][wc + 8] = h1;                                   \
    *(h8*)&WLs[buf][we][wc] = l0;                                       \
    *(h8*)&WLs[buf][we][wc + 8] = l1;                                   \
  }

#define CVT_X(slot)                                                    \
  {                                                                    \
    float xf[16] = {xreg[slot][0].x, xreg[slot][0].y, xreg[slot][0].z, \
                    xreg[slot][0].w, xreg[slot][1].x, xreg[slot][1].y, \
                    xreg[slot][1].z, xreg[slot][1].w, xreg[slot][2].x, \
                    xreg[slot][2].y, xreg[slot][2].z, xreg[slot][2].w, \
                    xreg[slot][3].x, xreg[slot][3].y, xreg[slot][3].z, \
                    xreg[slot][3].w};                                  \
    _Pragma("unroll") for (int j = 0; j < 8; j++) {                    \
      _Float16 a_ = (_Float16)xf[j];                                   \
      afh[slot][0][j] = a_;                                            \
      afl[slot][0][j] = (_Float16)((xf[j] - (float)a_) * 1024.f);      \
      _Float16 b_ = (_Float16)xf[j + 8];                               \
      afh[slot][1][j] = b_;                                            \
      afl[slot][1][j] = (_Float16)((xf[j + 8] - (float)b_) * 1024.f);  \
    }                                                                  \
  }

#define COMPUTE(buf, p)                                                      \
  {                                                                          \
    _Pragma("unroll") for (int ks = 0; ks < 2; ks++) {                       \
      _Pragma("unroll") for (int nt = 0; nt < 4; nt++) {                     \
        h8 bh = *(const h8*)&WHs[buf][nt * 16 + frow][ks * 32 + fk];         \
        h8 bl = *(const h8*)&WLs[buf][nt * 16 + frow][ks * 32 + fk];         \
        acc1[nt] = __builtin_amdgcn_mfma_f32_16x16x32_f16(afh[p][ks], bh,    \
                                                          acc1[nt], 0, 0, 0); \
        acc2[nt] = __builtin_amdgcn_mfma_f32_16x16x32_f16(afl[p][ks], bh,    \
                                                          acc2[nt], 0, 0, 0); \
        acc2[nt] = __builtin_amdgcn_mfma_f32_16x16x32_f16(afh[p][ks], bl,    \
                                                          acc2[nt], 0, 0, 0); \
      }                                                                      \
    }                                                                        \
  }

  // phase s (parity p == s&1): buf[p] holds W(s); af[p] holds x(s);
  // wreg/xreg[1-p] hold stage s+1 raw. Store s+1 -> buf[1-p], cvt x(s+1),
  // refill slot 1-p with stage s+3, compute stage s, one barrier.
#define PHASE(p, s)                 \
  {                                 \
    if ((s) + 1 < NSTAGE) {         \
      CVTSTORE_W(1 - (p), 1 - (p)); \
      CVT_X(1 - (p));               \
    }                               \
    if ((s) + 3 < NSTAGE) {         \
      LOAD_W(1 - (p), (s) + 3);     \
      LOAD_X(1 - (p), (s) + 3);     \
    }                               \
    COMPUTE((p), (p));              \
    __syncthreads();                \
  }

  // prologue
  LOAD_W(0, 0);
  LOAD_X(0, 0);
  LOAD_W(1, 1);
  LOAD_X(1, 1);
  CVTSTORE_W(0, 0);  // W(0) -> buf0
  CVT_X(0);          // x(0) -> af[0]
  LOAD_W(0, 2);
  LOAD_X(0, 2);
  __syncthreads();

  for (int it = 0; it < NSTAGE; it += 2) {
    PHASE(0, it);
    PHASE(1, it + 1);
  }

  // epilogue: C layout col=lane&15 (expert), row=(lane>>4)*4+r (token)
  const int cg = lane >> 4, ci = lane & 15;
#pragma unroll
  for (int nt = 0; nt < 4; nt++)
#pragma unroll
    for (int r = 0; r < 4; r++) {
      const float v =
          (acc1[nt][r] + acc2[nt][r] * 0.0009765625f) * 0.0009765625f;
      slog[wid * 16 + cg * 4 + r][nt * 16 + ci] = v;  // wave-local rows
    }

  // ---- softmax / top2 / hist / z tail (per-token, wave-local) ----
  float z_acc = 0.f;
  for (int tt = 0; tt < 16; tt++) {
    const int tloc = wid * 16 + tt;
    const int n = m0 + tloc;
    const float v = slog[tloc][lane];
    z_acc += v * v;
    float mx = v;
#pragma unroll
    for (int off = 32; off; off >>= 1) mx = fmaxf(mx, __shfl_xor(mx, off));
    const float p = __expf(v - mx);
    float ssum = p;
#pragma unroll
    for (int off = 32; off; off >>= 1) ssum += __shfl_xor(ssum, off);
    const float rw = p / ssum;
    rw_out[(size_t)n * N_EXP + lane] = rw;

    const unsigned long long b1 = __ballot(v == mx);
    const int i1 = __builtin_ctzll(b1);
    float v2 = (lane == i1) ? -INFINITY : v;
#pragma unroll
    for (int off = 32; off; off >>= 1) v2 = fmaxf(v2, __shfl_xor(v2, off));
    const unsigned long long b2 = __ballot(v == v2) & ~(1ull << i1);
    const int i2 = __builtin_ctzll(b2);
    const float rw1 = __shfl(rw, i1);
    const float rw2 = __shfl(rw, i2);
    if (lane == 0) {
      const float denom = rw1 + rw2 + 1e-8f;
      top12[n] = make_int2(i1, i2);
      wts[n] = make_float2(rw1 / denom, rw2 / denom);
      atomicAdd(&histR[(rep * N_EXP + i1) * 16], 1);
    }
  }
#pragma unroll
  for (int off = 32; off; off >>= 1) z_acc += __shfl_xor(z_acc, off);
  if (lane == 0) zred[wid] = z_acc;
  __syncthreads();
  if (t == 0) atomicAdd(&zR[rep * 16], zred[0] + zred[1] + zred[2] + zred[3]);
}

// ---------------- K3: wave-per-token dispatch mask + counts -----------------
__global__ __launch_bounds__(256) void k3_dispatch(
    const int2* __restrict__ top12, const float2* __restrict__ wts,
    const int* __restrict__ histR, float* __restrict__ mask_out,
    float* __restrict__ cntR) {
  const int lane = threadIdx.x & 63;
  const int wid = threadIdx.x >> 6;
  const int n = blockIdx.x * 4 + wid;
  const int rep = blockIdx.x & (NREP - 1);

  const int2 ij = top12[n];
  const float2 w = wts[n];
  int h = 0;
#pragma unroll
  for (int r = 0; r < NREP; r++) h += histR[(r * N_EXP + ij.y) * 16];
  const bool allowed = h < CAPACITY;
  const float ssum = w.x + (allowed ? w.y : 0.f);
  const float inv = 1.f / (ssum + 1e-8f);
  float val = 0.f;
  if (lane == ij.x) val = w.x * inv;
  else if (allowed && lane == ij.y) val = w.y * inv;
  mask_out[(size_t)n * N_EXP + lane] = val;
  if (val != 0.f) atomicAdd(&cntR[(rep * N_EXP + lane) * 16], val);
}

// ---------------- K4: scalar loss -------------------------------------------
__global__ void k4_loss(const float* __restrict__ cntR,
                        const float* __restrict__ zR,
                        float* __restrict__ loss_out) {
  const int lane = threadIdx.x;
  float c = 0.f;
#pragma unroll
  for (int r = 0; r < NREP; r++) c += cntR[(r * N_EXP + lane) * 16];
  const float d = (c - 512.0f) * (1.0f / 16384.0f);
  float v = d * d;
#pragma unroll
  for (int off = 32; off; off >>= 1) v += __shfl_xor(v, off);
  if (lane == 0) {
    float z = 0.f;
#pragma unroll
    for (int r = 0; r < NREP; r++) z += zR[r * 16];
    const float lb = v * (1.0f / 64.0f);
    loss_out[0] = 0.001f * (z * (1.0f / (16384.0f * 64.0f))) + 0.001f * lb;
  }
}

extern "C" void kernel_launch(void* const* d_in, const int* in_sizes, int n_in,
                              void* d_out, int out_size, void* d_ws,
                              size_t ws_size, hipStream_t stream) {
  const float* x = (const float*)d_in[0];
  const float* W = (const float*)d_in[1];
  float* out = (float*)d_out;
  float* rw_out = out;
  float* mask_out = out + (size_t)N_TOK * N_EXP;
  float* loss_out = out + 2 * (size_t)N_TOK * N_EXP;

  char* ws = (char*)d_ws;
  int* histR = (int*)ws;                 // 32 KB (8 reps x 64 x stride16)
  float* cntR = (float*)(ws + 32768);    // 32 KB
  float* zR = (float*)(ws + 65536);      // 512 B
  int2* top12 = (int2*)(ws + 131072);    // 128 KB
  float2* wts = (float2*)(ws + 262144);  // 128 KB

  hipMemsetAsync(histR, 0, 65536 + 512, stream);
  k12_gemm_softmax<<<256, 256, 0, stream>>>(x, W, rw_out, top12, wts, histR,
                                            zR);
  k3_dispatch<<<N_TOK / 4, 256, 0, stream>>>(top12, wts, histR, mask_out,
                                             cntR);
  k4_loss<<<1, 64, 0, stream>>>(cntR, zR, loss_out);
}

// Round 3
// 222.486 us; speedup vs baseline: 1.0270x; 1.0270x over previous
//
#include <hip/hip_runtime.h>
#include <math.h>

#define N_TOK 16384
#define D_MODEL 2048
#define N_EXP 64
#define CAPACITY 640
#define NREP 8

#define BK 64
#define NSTAGE (D_MODEL / BK)  // 32
#define LPW 72                 // W LDS row pitch in halves (144B)

typedef __attribute__((ext_vector_type(8))) _Float16 h8;
typedef __attribute__((ext_vector_type(4))) float f4;

// ---------------- K0: one-time W fp16 hi/lo split (W' = W*2^10) -------------
__global__ __launch_bounds__(256) void k0_cvtw(const float* __restrict__ W,
                                               _Float16* __restrict__ WHg,
                                               _Float16* __restrict__ WLg) {
  const int i = (blockIdx.x * 256 + threadIdx.x) * 8;
  const float4 a = *(const float4*)(W + i);
  const float4 b = *(const float4*)(W + i + 4);
  const float f[8] = {a.x, a.y, a.z, a.w, b.x, b.y, b.z, b.w};
  h8 hh, ll;
#pragma unroll
  for (int j = 0; j < 8; j++) {
    const float s = f[j] * 1024.f;
    const _Float16 h = (_Float16)s;
    hh[j] = h;
    ll[j] = (_Float16)((s - (float)h) * 1024.f);
  }
  *(h8*)(WHg + i) = hh;
  *(h8*)(WLg + i) = ll;
}

// ---------------- K12: fused MFMA fp16-split GEMM + softmax/top2/hist/z -----
// 512 blocks x 256 thr; block = 32 tokens x 64 experts x K=2048.
// Wave (wm,wn) owns 16 tokens x 32 experts. x: global->reg (A-frag layout).
// W: pre-split fp16 from k0, LDS double-buffered, 1 barrier/stage.
__global__ __launch_bounds__(256, 2) void k12_gemm_softmax(
    const float* __restrict__ x, const _Float16* __restrict__ WHg,
    const _Float16* __restrict__ WLg, float* __restrict__ rw_out,
    int2* __restrict__ top12, float2* __restrict__ wts,
    int* __restrict__ histR, float* __restrict__ zR) {
  __shared__ __align__(16) _Float16 WHs[2][64][LPW];
  __shared__ __align__(16) _Float16 WLs[2][64][LPW];
  __shared__ float slog[32][65];
  __shared__ float zred[4];

  const int t = threadIdx.x;
  const int lane = t & 63;
  const int wid = t >> 6;
  const int wm = wid >> 1;  // token half
  const int wn = wid & 1;   // expert half
  const int m0 = blockIdx.x * 32;
  const int rep = blockIdx.x & (NREP - 1);

  const int we = t >> 2;         // W staging: expert row
  const int wcc = (t & 3) * 16;  // W staging: col base (halves, 32B)
  const int frow = lane & 15;    // fragment row
  const int fk = (lane >> 4) * 8;

  const _Float16* whg = WHg + (size_t)we * D_MODEL + wcc;
  const _Float16* wlg = WLg + (size_t)we * D_MODEL + wcc;
  const float* xg = x + (size_t)(m0 + wm * 16 + frow) * D_MODEL + fk;

  h8 wh[2][2], wl[2][2];
  float4 xreg[2][4];
  h8 afh[2][2], afl[2][2];
  f4 acc1[2], acc2[2];
#pragma unroll
  for (int i = 0; i < 2; i++) {
    acc1[i] = (f4)(0.f);
    acc2[i] = (f4)(0.f);
  }

#define LOAD_W(slot, s)                             \
  {                                                 \
    const _Float16* ph_ = whg + (s) * BK;           \
    const _Float16* pl_ = wlg + (s) * BK;           \
    wh[slot][0] = *(const h8*)(ph_);                \
    wh[slot][1] = *(const h8*)(ph_ + 8);            \
    wl[slot][0] = *(const h8*)(pl_);                \
    wl[slot][1] = *(const h8*)(pl_ + 8);            \
  }
#define LOAD_X(slot, s)                        \
  {                                            \
    const float* p_ = xg + (s) * BK;           \
    xreg[slot][0] = *(const float4*)(p_);      \
    xreg[slot][1] = *(const float4*)(p_ + 4);  \
    xreg[slot][2] = *(const float4*)(p_ + 32); \
    xreg[slot][3] = *(const float4*)(p_ + 36); \
  }
#define STORE_W(slot, buf)                     \
  {                                            \
    *(h8*)&WHs[buf][we][wcc] = wh[slot][0];    \
    *(h8*)&WHs[buf][we][wcc + 8] = wh[slot][1]; \
    *(h8*)&WLs[buf][we][wcc] = wl[slot][0];    \
    *(h8*)&WLs[buf][we][wcc + 8] = wl[slot][1]; \
  }
#define CVT_X(slot)                                                    \
  {                                                                    \
    float xf[16] = {xreg[slot][0].x, xreg[slot][0].y, xreg[slot][0].z, \
                    xreg[slot][0].w, xreg[slot][1].x, xreg[slot][1].y, \
                    xreg[slot][1].z, xreg[slot][1].w, xreg[slot][2].x, \
                    xreg[slot][2].y, xreg[slot][2].z, xreg[slot][2].w, \
                    xreg[slot][3].x, xreg[slot][3].y, xreg[slot][3].z, \
                    xreg[slot][3].w};                                  \
    _Pragma("unroll") for (int j = 0; j < 8; j++) {                    \
      _Float16 a_ = (_Float16)xf[j];                                   \
      afh[slot][0][j] = a_;                                            \
      afl[slot][0][j] = (_Float16)((xf[j] - (float)a_) * 1024.f);      \
      _Float16 b_ = (_Float16)xf[j + 8];                               \
      afh[slot][1][j] = b_;                                            \
      afl[slot][1][j] = (_Float16)((xf[j + 8] - (float)b_) * 1024.f);  \
    }                                                                  \
  }
#define COMPUTE(buf, p)                                                       \
  {                                                                           \
    _Pragma("unroll") for (int ks = 0; ks < 2; ks++) {                        \
      _Pragma("unroll") for (int nt = 0; nt < 2; nt++) {                      \
        h8 bh = *(const h8*)&WHs[buf][wn * 32 + nt * 16 + frow][ks * 32 + fk]; \
        h8 bl = *(const h8*)&WLs[buf][wn * 32 + nt * 16 + frow][ks * 32 + fk]; \
        acc1[nt] = __builtin_amdgcn_mfma_f32_16x16x32_f16(afh[p][ks], bh,     \
                                                          acc1[nt], 0, 0, 0);  \
        acc2[nt] = __builtin_amdgcn_mfma_f32_16x16x32_f16(afl[p][ks], bh,     \
                                                          acc2[nt], 0, 0, 0);  \
        acc2[nt] = __builtin_amdgcn_mfma_f32_16x16x32_f16(afh[p][ks], bl,     \
                                                          acc2[nt], 0, 0, 0);  \
      }                                                                       \
    }                                                                         \
  }
#define PHASE(p, s)                 \
  {                                 \
    if ((s) + 1 < NSTAGE) {         \
      STORE_W(1 - (p), 1 - (p));    \
      CVT_X(1 - (p));               \
    }                               \
    if ((s) + 3 < NSTAGE) {         \
      LOAD_W(1 - (p), (s) + 3);     \
      LOAD_X(1 - (p), (s) + 3);     \
    }                               \
    COMPUTE((p), (p));              \
    __syncthreads();                \
  }

  // prologue
  LOAD_W(0, 0);
  LOAD_X(0, 0);
  LOAD_W(1, 1);
  LOAD_X(1, 1);
  STORE_W(0, 0);
  CVT_X(0);
  LOAD_W(0, 2);
  LOAD_X(0, 2);
  __syncthreads();

  for (int it = 0; it < NSTAGE; it += 2) {
    PHASE(0, it);
    PHASE(1, it + 1);
  }

  // epilogue: C layout col=lane&15 (expert), row=(lane>>4)*4+r (token)
  const int cg = lane >> 4, ci = lane & 15;
#pragma unroll
  for (int nt = 0; nt < 2; nt++)
#pragma unroll
    for (int r = 0; r < 4; r++) {
      const float v =
          (acc1[nt][r] + acc2[nt][r] * 0.0009765625f) * 0.0009765625f;
      slog[wm * 16 + cg * 4 + r][wn * 32 + nt * 16 + ci] = v;
    }
  __syncthreads();

  // ---- softmax / top2 / hist / z tail (8 tokens per wave) ----
  float z_acc = 0.f;
  for (int tt = 0; tt < 8; tt++) {
    const int tloc = wid * 8 + tt;
    const int n = m0 + tloc;
    const float v = slog[tloc][lane];
    z_acc += v * v;
    float mx = v;
#pragma unroll
    for (int off = 32; off; off >>= 1) mx = fmaxf(mx, __shfl_xor(mx, off));
    const float p = __expf(v - mx);
    float ssum = p;
#pragma unroll
    for (int off = 32; off; off >>= 1) ssum += __shfl_xor(ssum, off);
    const float rw = p / ssum;
    rw_out[(size_t)n * N_EXP + lane] = rw;

    const unsigned long long b1 = __ballot(v == mx);
    const int i1 = __builtin_ctzll(b1);
    float v2 = (lane == i1) ? -INFINITY : v;
#pragma unroll
    for (int off = 32; off; off >>= 1) v2 = fmaxf(v2, __shfl_xor(v2, off));
    const unsigned long long b2 = __ballot(v == v2) & ~(1ull << i1);
    const int i2 = __builtin_ctzll(b2);
    const float rw1 = __shfl(rw, i1);
    const float rw2 = __shfl(rw, i2);
    if (lane == 0) {
      const float denom = rw1 + rw2 + 1e-8f;
      top12[n] = make_int2(i1, i2);
      wts[n] = make_float2(rw1 / denom, rw2 / denom);
      atomicAdd(&histR[(rep * N_EXP + i1) * 16], 1);
    }
  }
#pragma unroll
  for (int off = 32; off; off >>= 1) z_acc += __shfl_xor(z_acc, off);
  if (lane == 0) zred[wid] = z_acc;
  __syncthreads();
  if (t == 0) atomicAdd(&zR[rep * 16], zred[0] + zred[1] + zred[2] + zred[3]);
}

// ---------------- K3: wave-per-token dispatch mask + counts -----------------
__global__ __launch_bounds__(256) void k3_dispatch(
    const int2* __restrict__ top12, const float2* __restrict__ wts,
    const int* __restrict__ histR, float* __restrict__ mask_out,
    float* __restrict__ cntR) {
  const int lane = threadIdx.x & 63;
  const int wid = threadIdx.x >> 6;
  const int n = blockIdx.x * 4 + wid;
  const int rep = blockIdx.x & (NREP - 1);

  const int2 ij = top12[n];
  const float2 w = wts[n];
  int h = 0;
#pragma unroll
  for (int r = 0; r < NREP; r++) h += histR[(r * N_EXP + ij.y) * 16];
  const bool allowed = h < CAPACITY;
  const float ssum = w.x + (allowed ? w.y : 0.f);
  const float inv = 1.f / (ssum + 1e-8f);
  float val = 0.f;
  if (lane == ij.x) val = w.x * inv;
  else if (allowed && lane == ij.y) val = w.y * inv;
  mask_out[(size_t)n * N_EXP + lane] = val;
  if (val != 0.f) atomicAdd(&cntR[(rep * N_EXP + lane) * 16], val);
}

// ---------------- K4: scalar loss -------------------------------------------
__global__ void k4_loss(const float* __restrict__ cntR,
                        const float* __restrict__ zR,
                        float* __restrict__ loss_out) {
  const int lane = threadIdx.x;
  float c = 0.f;
#pragma unroll
  for (int r = 0; r < NREP; r++) c += cntR[(r * N_EXP + lane) * 16];
  const float d = (c - 512.0f) * (1.0f / 16384.0f);
  float v = d * d;
#pragma unroll
  for (int off = 32; off; off >>= 1) v += __shfl_xor(v, off);
  if (lane == 0) {
    float z = 0.f;
#pragma unroll
    for (int r = 0; r < NREP; r++) z += zR[r * 16];
    const float lb = v * (1.0f / 64.0f);
    loss_out[0] = 0.001f * (z * (1.0f / (16384.0f * 64.0f))) + 0.001f * lb;
  }
}

extern "C" void kernel_launch(void* const* d_in, const int* in_sizes, int n_in,
                              void* d_out, int out_size, void* d_ws,
                              size_t ws_size, hipStream_t stream) {
  const float* x = (const float*)d_in[0];
  const float* W = (const float*)d_in[1];
  float* out = (float*)d_out;
  float* rw_out = out;
  float* mask_out = out + (size_t)N_TOK * N_EXP;
  float* loss_out = out + 2 * (size_t)N_TOK * N_EXP;

  char* ws = (char*)d_ws;
  int* histR = (int*)ws;                      // 32 KB
  float* cntR = (float*)(ws + 32768);         // 32 KB
  float* zR = (float*)(ws + 65536);           // 512 B
  int2* top12 = (int2*)(ws + 131072);         // 128 KB
  float2* wts = (float2*)(ws + 262144);       // 128 KB
  _Float16* WHg = (_Float16*)(ws + 393216);   // 256 KB
  _Float16* WLg = (_Float16*)(ws + 655360);   // 256 KB

  hipMemsetAsync(histR, 0, 65536 + 512, stream);
  k0_cvtw<<<64, 256, 0, stream>>>(W, WHg, WLg);
  k12_gemm_softmax<<<512, 256, 0, stream>>>(x, WHg, WLg, rw_out, top12, wts,
                                            histR, zR);
  k3_dispatch<<<N_TOK / 4, 256, 0, stream>>>(top12, wts, histR, mask_out,
                                             cntR);
  k4_loss<<<1, 64, 0, stream>>>(cntR, zR, loss_out);
}